// Round 7
// baseline (123.724 us; speedup 1.0000x reference)
//
#include <hip/hip_runtime.h>
#include <math.h>

#define ZD 16
#define PD 4
#define ND 466
#define HD 86
#define TD 4096
#define XD (ND + PD)   // 470
#define MGRID 2        // uniform RK4 cells — total err ~1e-3 << bf16 floor

// ---------------------------------------------------------------------------
// Single fused kernel, 512 independent blocks. EVERY block redundantly
// computes the encoder + layer-2 + RK4 (cheap: ~6 us, overlapped across
// blocks) into its own LDS, then decodes its 16t x 256n tile. No inter-block
// communication at all (R5 showed a global-flag spin causes an XCD
// invalidate storm; redundancy is free by comparison). No ws usage.
// ---------------------------------------------------------------------------
__global__ __launch_bounds__(256) void fused_kernel(
    const float* __restrict__ n0, const float* __restrict__ p,
    const float* __restrict__ tstep,
    const float* __restrict__ A, const float* __restrict__ Bt,
    const float* __restrict__ We1, const float* __restrict__ be1,
    const float* __restrict__ We2, const float* __restrict__ be2,
    const float* __restrict__ Wd1, const float* __restrict__ bd1,
    const float* __restrict__ Wd2, const float* __restrict__ bd2,
    float* __restrict__ out)
{
    const int tid = threadIdx.x;
    const int idx = blockIdx.x;            // 0..511
    const int tbase = (idx >> 1) * 16;
    const int nblk = idx & 1;

    __shared__ float red[2][HD];
    __shared__ float sa[HD];
    __shared__ float zgs[MGRID + 1][ZD];
    __shared__ float ggs[MGRID + 1][ZD];
    __shared__ float szt[16][ZD];
    __shared__ float saT[HD][16];          // [h][tl] transposed

    const float t0 = tstep[0];
    const float tM = tstep[TD - 1];
    const float hg = (tM - t0) / (float)MGRID;

    // ---- encoder layer 1: c = row-half, hh = hidden unit (coalesced) ----
    {
        const int c  = tid >> 7;           // 0 or 1
        const int hh = tid & 127;
        if (hh < HD) {
            const int r0 = c * 235;
            const int r1 = r0 + 235;
            float acc = 0.f;
            for (int r = r0; r < r1; ++r) {
                const float x = (r < PD) ? p[r] : n0[r - PD];  // wave-uniform
                acc = fmaf(x, We1[r * HD + hh], acc);
            }
            red[c][hh] = acc;
        }
    }
    __syncthreads();
    if (tid < HD)
        sa[tid] = tanhf(red[0][tid] + red[1][tid] + be1[tid]);
    __syncthreads();

    // ---- wave 0: layer 2 + RK4 into LDS ----
    if (tid < 64) {
        const int lane = tid;
        const int ci = lane & 15;
        const int jg = lane >> 4;

        float Areg[4], Breg[64];
        #pragma unroll
        for (int jj = 0; jj < 4; ++jj) {
            const int j = jg * 4 + jj;
            Areg[jj] = A[ci * ZD + j];
            #pragma unroll
            for (int k = 0; k < ZD; ++k)
                Breg[jj * 16 + k] = Bt[ci * 256 + j * 16 + k];
        }

        float zd;
        {
            const int hlo = jg * 22;
            const int hhi = (hlo + 22 < HD) ? hlo + 22 : HD;
            float acc = 0.f;
            for (int h = hlo; h < hhi; ++h)
                acc = fmaf(sa[h], We2[h * ZD + ci], acc);
            acc += __shfl_xor(acc, 16, 64);
            acc += __shfl_xor(acc, 32, 64);
            zd = tanhf(acc + be2[ci]);     // every lane: z0[ci]
        }

        // g(y)_i = sum_j y_j * (A[i,j] + sum_k B[i,j,k] y_k)
        auto geval = [&](float yd) -> float {
            float yk[16];
            #pragma unroll
            for (int k = 0; k < 16; ++k) yk[k] = __shfl(yd, k, 64);
            float acc = 0.f;
            #pragma unroll
            for (int jj = 0; jj < 4; ++jj) {
                float tt = Areg[jj];
                #pragma unroll
                for (int k = 0; k < 16; ++k)
                    tt = fmaf(Breg[jj * 16 + k], yk[k], tt);
                float yj = __shfl(yd, jg * 4 + jj, 64);
                acc = fmaf(yj, tt, acc);
            }
            acc += __shfl_xor(acc, 16, 64);
            acc += __shfl_xor(acc, 32, 64);
            return acc;
        };

        for (int node = 0; node <= MGRID; ++node) {
            const float k1 = geval(zd);
            if (lane < ZD) {
                zgs[node][lane] = zd;
                ggs[node][lane] = k1;
            }
            if (node == MGRID) break;
            float y = fmaf(0.5f * hg, k1, zd);
            const float k2 = geval(y);
            y = fmaf(0.5f * hg, k2, zd);
            const float k3 = geval(y);
            y = fmaf(hg, k3, zd);
            const float k4 = geval(y);
            zd = fmaf(hg * (1.0f / 6.0f), k1 + 2.f * k2 + 2.f * k3 + k4, zd);
        }
    }
    __syncthreads();

    // ---- cubic Hermite interpolation of z(t): 16t x 16z = 256 units ----
    {
        const int tl = tid >> 4;
        const int c  = tid & 15;
        const float t = tstep[tbase + tl];
        const float u = (t - t0) / hg;
        int cell = (int)u;
        if (cell < 0) cell = 0;
        if (cell > MGRID - 1) cell = MGRID - 1;
        float s = u - (float)cell;
        if (s < 0.f) s = 0.f;
        if (s > 1.f) s = 1.f;
        const float za = zgs[cell][c];
        const float zb = zgs[cell + 1][c];
        const float ga = ggs[cell][c];
        const float gb = ggs[cell + 1][c];
        const float s2 = s * s, s3 = s2 * s;
        const float h00 = 2.f * s3 - 3.f * s2 + 1.f;
        const float h10 = s3 - 2.f * s2 + s;
        const float h01 = -2.f * s3 + 3.f * s2;
        const float h11 = s3 - s2;
        szt[tl][c] = h00 * za + hg * h10 * ga + h01 * zb + hg * h11 * gb;
    }
    __syncthreads();

    // ---- hidden layer: saT[h][tl] = tanh(z[tl] . Wd1[:,h] + bd1[h]) ----
    for (int u = tid; u < 16 * HD; u += 256) {
        const int tl = u / HD;
        const int h  = u - tl * HD;
        float acc = bd1[h];
        #pragma unroll
        for (int i = 0; i < ZD; ++i)
            acc = fmaf(szt[tl][i], Wd1[i * HD + h], acc);
        saT[h][tl] = tanhf(acc);
    }
    __syncthreads();

    // ---- output layer: thread = (tt, tn) owns 4t x 4n register tile ----
    const int tn = tid & 63;
    const int tt = tid >> 6;
    const int nb = nblk * 256 + tn * 4;
    const int a0 = (nb <= 464) ? nb : 464;       // clamped 8B-aligned loads
    const int a1 = (nb + 2 <= 464) ? nb + 2 : 0;

    float b2[4];
    #pragma unroll
    for (int c = 0; c < 4; ++c) {
        int n = nb + c; if (n > ND - 1) n = ND - 1;
        b2[c] = bd2[n];
    }
    float acc[4][4];
    #pragma unroll
    for (int q = 0; q < 4; ++q)
        #pragma unroll
        for (int c = 0; c < 4; ++c) acc[q][c] = b2[c];

    for (int h = 0; h < HD; ++h) {
        const float4 av = *(const float4*)&saT[h][tt * 4];   // broadcast b128
        const float* row = Wd2 + h * ND;
        const float2 w0 = *(const float2*)(row + a0);
        const float2 w1 = *(const float2*)(row + a1);
        const float wv[4] = {w0.x, w0.y, w1.x, w1.y};
        const float avq[4] = {av.x, av.y, av.z, av.w};
        #pragma unroll
        for (int q = 0; q < 4; ++q)
            #pragma unroll
            for (int c = 0; c < 4; ++c)
                acc[q][c] = fmaf(avq[q], wv[c], acc[q][c]);
    }

    #pragma unroll
    for (int q = 0; q < 4; ++q) {
        const int t = tbase + tt * 4 + q;
        #pragma unroll
        for (int c = 0; c < 4; ++c) {
            const int n = nb + c;
            if (n < ND) out[(size_t)t * ND + n] = acc[q][c];
        }
    }
}

// ---------------------------------------------------------------------------
extern "C" void kernel_launch(void* const* d_in, const int* in_sizes, int n_in,
                              void* d_out, int out_size, void* d_ws, size_t ws_size,
                              hipStream_t stream)
{
    const float* n0  = (const float*)d_in[0];
    const float* p   = (const float*)d_in[1];
    const float* ts  = (const float*)d_in[2];
    const float* A   = (const float*)d_in[3];
    const float* B   = (const float*)d_in[4];
    const float* We1 = (const float*)d_in[5];
    const float* be1 = (const float*)d_in[6];
    const float* We2 = (const float*)d_in[7];
    const float* be2 = (const float*)d_in[8];
    const float* Wd1 = (const float*)d_in[9];
    const float* bd1 = (const float*)d_in[10];
    const float* Wd2 = (const float*)d_in[11];
    const float* bd2 = (const float*)d_in[12];

    float* out = (float*)d_out;

    hipLaunchKernelGGL(fused_kernel, dim3(TD / 16 * 2), dim3(256), 0, stream,
                       n0, p, ts, A, B, We1, be1, We2, be2,
                       Wd1, bd1, Wd2, bd2, out);
}

// Round 8
// 121.991 us; speedup vs baseline: 1.0142x; 1.0142x over previous
//
#include <hip/hip_runtime.h>
#include <math.h>

#define ZD 16
#define PD 4
#define ND 466
#define HD 86
#define TD 4096
#define XD (ND + PD)   // 470
#define MGRID 2        // uniform RK4 cells — total err ~1e-3 << bf16 floor

// ---------------------------------------------------------------------------
// Kernel 1: encoder (256-thread coalesced GEMV) + layer 2 + RK4 (1 block).
// Stream order is the solver->decode sync (R5: global-flag spin = invalidate
// storm; R7: per-block redundant solver = +6us on every block's path).
// ---------------------------------------------------------------------------
__global__ __launch_bounds__(256) void solver_kernel(
    const float* __restrict__ n0, const float* __restrict__ p,
    const float* __restrict__ tstep,
    const float* __restrict__ A, const float* __restrict__ Bt,
    const float* __restrict__ We1, const float* __restrict__ be1,
    const float* __restrict__ We2, const float* __restrict__ be2,
    float* __restrict__ zg, float* __restrict__ gg)
{
    const int tid = threadIdx.x;

    __shared__ float red[2][HD];
    __shared__ float sa[HD];

    // ---- encoder layer 1: c = row-half, hh = hidden unit (coalesced) ----
    const int c  = tid >> 7;          // 0 or 1
    const int hh = tid & 127;
    if (hh < HD) {
        const int r0 = c * 235;
        const int r1 = r0 + 235;
        float acc = 0.f;
        for (int r = r0; r < r1; ++r) {
            const float x = (r < PD) ? p[r] : n0[r - PD];   // wave-uniform
            acc = fmaf(x, We1[r * HD + hh], acc);
        }
        red[c][hh] = acc;
    }
    __syncthreads();
    if (tid < HD)
        sa[tid] = tanhf(red[0][tid] + red[1][tid] + be1[tid]);
    __syncthreads();

    if (tid >= 64) return;

    const int lane = tid;
    const int ci = lane & 15;
    const int jg = lane >> 4;

    // ---- per-lane vector-field coefficients ----
    float Areg[4], Breg[64];
    #pragma unroll
    for (int jj = 0; jj < 4; ++jj) {
        const int j = jg * 4 + jj;
        Areg[jj] = A[ci * ZD + j];
        #pragma unroll
        for (int k = 0; k < ZD; ++k)
            Breg[jj * 16 + k] = Bt[ci * 256 + j * 16 + k];
    }
    const float t0 = tstep[0];
    const float tM = tstep[TD - 1];
    const float hg = (tM - t0) / (float)MGRID;

    // ---- layer 2: 4 h-chunks (part = jg), butterfly-combined ----
    float zd;
    {
        const int hlo = jg * 22;
        const int hhi = (hlo + 22 < HD) ? hlo + 22 : HD;
        float acc = 0.f;
        for (int h = hlo; h < hhi; ++h)
            acc = fmaf(sa[h], We2[h * ZD + ci], acc);
        acc += __shfl_xor(acc, 16, 64);
        acc += __shfl_xor(acc, 32, 64);
        zd = tanhf(acc + be2[ci]);     // every lane: z0[ci]
    }

    // g(y)_i = sum_j y_j * (A[i,j] + sum_k B[i,j,k] y_k), distributed eval
    auto geval = [&](float yd) -> float {
        float yk[16];
        #pragma unroll
        for (int k = 0; k < 16; ++k) yk[k] = __shfl(yd, k, 64);
        float acc = 0.f;
        #pragma unroll
        for (int jj = 0; jj < 4; ++jj) {
            float tt = Areg[jj];
            #pragma unroll
            for (int k = 0; k < 16; ++k)
                tt = fmaf(Breg[jj * 16 + k], yk[k], tt);
            float yj = __shfl(yd, jg * 4 + jj, 64);
            acc = fmaf(yj, tt, acc);
        }
        acc += __shfl_xor(acc, 16, 64);
        acc += __shfl_xor(acc, 32, 64);
        return acc;
    };

    for (int node = 0; node <= MGRID; ++node) {
        const float k1 = geval(zd);
        if (lane < ZD) {
            zg[node * ZD + lane] = zd;
            gg[node * ZD + lane] = k1;
        }
        if (node == MGRID) break;
        float y = fmaf(0.5f * hg, k1, zd);
        const float k2 = geval(y);
        y = fmaf(0.5f * hg, k2, zd);
        const float k3 = geval(y);
        y = fmaf(hg, k3, zd);
        const float k4 = geval(y);
        zd = fmaf(hg * (1.0f / 6.0f), k1 + 2.f * k2 + 2.f * k3 + k4, zd);
    }
}

// ---------------------------------------------------------------------------
// Kernel 2: Hermite dense-output + decoder, occupancy-tuned.
// Block = 16t x 128n, thread = 4t x 2n (8 out) -> 1024 blocks x 4 waves =
// 4096 waves = 4/SIMD (R7 had 1.8/SIMD -> 18% VALUBusy, latency-bound).
// saT stride 20 (16B-aligned rows) + h-major write indexing: kills the
// 297k-cycle 32-way bank conflict (consecutive lanes now write consecutive
// banks). Main-loop saT read is wave-uniform (tt constant per wave) = free
// broadcast; Wd2 read = one aligned float2/lane/h, 512B/wave contiguous.
// ---------------------------------------------------------------------------
__global__ __launch_bounds__(256) void decode_kernel(
    const float* __restrict__ tstep,
    const float* __restrict__ zg, const float* __restrict__ gg,
    const float* __restrict__ Wd1, const float* __restrict__ bd1,
    const float* __restrict__ Wd2, const float* __restrict__ bd2,
    float* __restrict__ out)
{
    const int tid = threadIdx.x;
    const int tbase = blockIdx.x * 16;
    const int nbase = blockIdx.y * 128;

    __shared__ float sztT[ZD][17];      // [z-comp][tl], stride 17: bank-clean
    __shared__ float saT[HD][20];       // [h][tl], stride 20: 16B-aligned rows

    const float t0 = tstep[0];
    const float tM = tstep[TD - 1];
    const float hg = (tM - t0) / (float)MGRID;
    const float inv_hg = 1.0f / hg;

    // ---- cubic Hermite interpolation of z(t): 16t x 16z = 256 units ----
    {
        const int tl = tid >> 4;
        const int c  = tid & 15;
        const float t = tstep[tbase + tl];
        const float u = (t - t0) * inv_hg;
        int cell = (int)u;
        if (cell < 0) cell = 0;
        if (cell > MGRID - 1) cell = MGRID - 1;
        float s = u - (float)cell;
        if (s < 0.f) s = 0.f;
        if (s > 1.f) s = 1.f;
        const float za = zg[cell * ZD + c];
        const float zb = zg[(cell + 1) * ZD + c];
        const float ga = gg[cell * ZD + c];
        const float gb = gg[(cell + 1) * ZD + c];
        const float s2 = s * s, s3 = s2 * s;
        const float h00 = 2.f * s3 - 3.f * s2 + 1.f;
        const float h10 = s3 - 2.f * s2 + s;
        const float h01 = -2.f * s3 + 3.f * s2;
        const float h11 = s3 - s2;
        sztT[c][tl] = h00 * za + hg * h10 * ga + h01 * zb + hg * h11 * gb;
    }
    __syncthreads();

    // ---- hidden layer, h-major: consecutive lanes -> consecutive tl ----
    for (int u = tid; u < 16 * HD; u += 256) {
        const int tl = u & 15;
        const int h  = u >> 4;
        float acc = bd1[h];
        #pragma unroll
        for (int i = 0; i < ZD; ++i)
            acc = fmaf(sztT[i][tl], Wd1[i * HD + h], acc);
        saT[h][tl] = tanhf(acc);        // banks 0..15 + 20-offset groups: ~free
    }
    __syncthreads();

    // ---- output layer: thread = (tt, tn) owns 4t x 2n register tile ----
    const int tn = tid & 63;
    const int tt = tid >> 6;            // wave-uniform (tid 0-63 -> tt=0 etc)
    const int nb = nbase + tn * 2;      // even -> 8B-aligned
    const int nc = (nb <= ND - 2) ? nb : ND - 2;   // clamped load addr

    float acc[4][2];
    {
        const float b0 = bd2[nc];
        const float b1 = bd2[nc + 1];
        #pragma unroll
        for (int q = 0; q < 4; ++q) { acc[q][0] = b0; acc[q][1] = b1; }
    }

    #pragma unroll 2
    for (int h = 0; h < HD; ++h) {
        const float4 av = *(const float4*)&saT[h][tt * 4];  // wave-broadcast
        const float2 w  = *(const float2*)(Wd2 + h * ND + nc);
        const float avq[4] = {av.x, av.y, av.z, av.w};
        #pragma unroll
        for (int q = 0; q < 4; ++q) {
            acc[q][0] = fmaf(avq[q], w.x, acc[q][0]);
            acc[q][1] = fmaf(avq[q], w.y, acc[q][1]);
        }
    }

    if (nb <= ND - 2) {                 // pair fully in-bounds (nb even)
        #pragma unroll
        for (int q = 0; q < 4; ++q) {
            const int t = tbase + tt * 4 + q;
            float2 v = {acc[q][0], acc[q][1]};
            *(float2*)(out + (size_t)t * ND + nb) = v;      // 8B-aligned
        }
    }
}

// ---------------------------------------------------------------------------
extern "C" void kernel_launch(void* const* d_in, const int* in_sizes, int n_in,
                              void* d_out, int out_size, void* d_ws, size_t ws_size,
                              hipStream_t stream)
{
    const float* n0  = (const float*)d_in[0];
    const float* p   = (const float*)d_in[1];
    const float* ts  = (const float*)d_in[2];
    const float* A   = (const float*)d_in[3];
    const float* B   = (const float*)d_in[4];
    const float* We1 = (const float*)d_in[5];
    const float* be1 = (const float*)d_in[6];
    const float* We2 = (const float*)d_in[7];
    const float* be2 = (const float*)d_in[8];
    const float* Wd1 = (const float*)d_in[9];
    const float* bd1 = (const float*)d_in[10];
    const float* Wd2 = (const float*)d_in[11];
    const float* bd2 = (const float*)d_in[12];

    float* out = (float*)d_out;
    float* zg  = (float*)d_ws;                    // (MGRID+1) x 16
    float* gg  = zg + (MGRID + 1) * ZD;           // (MGRID+1) x 16

    hipLaunchKernelGGL(solver_kernel, dim3(1), dim3(256), 0, stream,
                       n0, p, ts, A, B, We1, be1, We2, be2, zg, gg);
    hipLaunchKernelGGL(decode_kernel, dim3(TD / 16, 4), dim3(256), 0, stream,
                       ts, zg, gg, Wd1, bd1, Wd2, bd2, out);
}